// Round 5
// baseline (330.449 us; speedup 1.0000x reference)
//
#include <hip/hip_runtime.h>

// out = x + alpha * softmax(beta * x @ K^T) @ V
// B=4096, N=16384, D=1024, fp32 in/out.
// R7 changes vs R6:
//  - GEMM epilogue additionally emits M[row][seg] = max over the block's 256
//    cols of beta*C (seg == bn). Near-free: acc is in registers; LDS 256x65
//    f32 scratch (reused sm) + one 1KB global write per block.
//  - softmax rewritten (softmax_gather2): one WAVE per row. Reads the 64
//    segment maxes (256B), reduces -> m; scans ONLY segments with
//    Mseg >= m-15 (typically 1-3 of 64) for BOTH the denominator l and the
//    selection. Omitted mass <= N*3e-7 ~ 0.5% of l — same truncation bound
//    already accepted. S read: 128 MB -> ~5 MB. V gather/X/Out unchanged.
//  - GEMM core schedule byte-identical to R6 (141.5us / MfmaUtil 41.6 / 0
//    conflicts — verified passing 3 rounds).

typedef float    f32x4  __attribute__((ext_vector_type(4)));
typedef _Float16 f16x8  __attribute__((ext_vector_type(8)));
typedef _Float16 f16x4  __attribute__((ext_vector_type(4)));

#define LOG2E 1.44269504088896340736f
#define KK 1024   // K (= D) fixed for this problem shape
#define NT 16     // K-tiles of 64
#define SELCAP 512

__device__ __forceinline__ void lds_load16(const void* g, void* l) {
    __builtin_amdgcn_global_load_lds(
        (__attribute__((address_space(1))) void*)(uintptr_t)g,
        (__attribute__((address_space(3))) void*)l,
        16, 0, 0);
}

template<int N> __device__ __forceinline__ void vwait() {
    if constexpr (N == 8)      asm volatile("s_waitcnt vmcnt(8)" ::: "memory");
    else if constexpr (N == 6) asm volatile("s_waitcnt vmcnt(6)" ::: "memory");
    else if constexpr (N == 4) asm volatile("s_waitcnt vmcnt(4)" ::: "memory");
    else if constexpr (N == 0) asm volatile("s_waitcnt vmcnt(0)" ::: "memory");
    // N == -1: no wait
}

__device__ __forceinline__ float fexp2(float x) {
    float r; asm("v_exp_f32 %0, %1" : "=v"(r) : "v"(x)); return r;
}

__global__ void convert2(const float* __restrict__ a, _Float16* __restrict__ oa, long na4,
                         const float* __restrict__ b, _Float16* __restrict__ ob, long nb4) {
    long i = (long)blockIdx.x * blockDim.x + threadIdx.x;
    if (i < na4) {
        ((f16x4*)oa)[i] = __builtin_convertvector(((const f32x4*)a)[i], f16x4);
    } else {
        long j = i - na4;
        if (j < nb4) ((f16x4*)ob)[j] = __builtin_convertvector(((const f32x4*)b)[j], f16x4);
    }
}

// Stage one half-tile (128 rows x 64 halves) of row-major [*, KK] f16 into LDS.
// LDS side lane-linear (global_load_lds requirement); chunk rotation
// slot=(chunk+row)&7 realized by rotating the GLOBAL source column.
// One call = 2 vmcnt entries.
__device__ __forceinline__ void stage_half(const _Float16* __restrict__ g,
                                           int k0, _Float16* lds_half, int tid) {
    const int r = tid >> 3;                        // 0..63
    const int c = ((tid & 7) - (r & 7)) & 7;       // source chunk for slot tid&7
    const _Float16* s0 = g + (long)r * KK + k0 + c * 8;
    _Float16* d = lds_half + (tid >> 6) * 512;     // wave-uniform base; HW adds lane*16B
    lds_load16(s0, d);
    lds_load16(s0 + 64 * KK, d + 4096);
}

// One K-tile (BK=64) of the 8-phase schedule (reads at phase head, barrier +
// lgkmcnt(0) hides their latency). Ac/Bc: current LDS buffer; An/Bn: other.
template<bool IA1, bool IB1, bool IA0, bool IB0, int D2, int D1>
__device__ __forceinline__ void tile_body(
    _Float16* Ac, _Float16* Bc, _Float16* An, _Float16* Bn,
    const _Float16* __restrict__ Ag, const _Float16* __restrict__ Bg, int kt,
    const int (&aoff)[4][2], const int (&boff)[2][2],
    int tid, f32x4 (&acc)[2][4][2][2])
{
    f16x8 a[4][2];
    f16x8 b[2][2][2];

    // ---- P1: quadrant (mh=0, nh=0) ----
#pragma unroll
    for (int mi = 0; mi < 4; ++mi)
#pragma unroll
        for (int ks = 0; ks < 2; ++ks)
            a[mi][ks] = *(const f16x8*)&Ac[aoff[mi][ks]];
#pragma unroll
    for (int nj = 0; nj < 2; ++nj)
#pragma unroll
        for (int ks = 0; ks < 2; ++ks)
            b[0][nj][ks] = *(const f16x8*)&Bc[boff[nj][ks]];
    if (IA1) stage_half(Ag + 128L * KK, (kt + 1) * 64, An + 8192, tid);
    __builtin_amdgcn_s_barrier();
    asm volatile("s_waitcnt lgkmcnt(0)" ::: "memory");
    __builtin_amdgcn_sched_barrier(0);
    __builtin_amdgcn_s_setprio(1);
#pragma unroll
    for (int mi = 0; mi < 4; ++mi)
#pragma unroll
        for (int nj = 0; nj < 2; ++nj)
#pragma unroll
            for (int ks = 0; ks < 2; ++ks)
                acc[0][mi][0][nj] = __builtin_amdgcn_mfma_f32_16x16x32_f16(
                    a[mi][ks], b[0][nj][ks], acc[0][mi][0][nj], 0, 0, 0);
    __builtin_amdgcn_s_setprio(0);
    vwait<D2>();
    __builtin_amdgcn_s_barrier();

    // ---- P2: quadrant (0,1) ----
#pragma unroll
    for (int nj = 0; nj < 2; ++nj)
#pragma unroll
        for (int ks = 0; ks < 2; ++ks)
            b[1][nj][ks] = *(const f16x8*)&Bc[boff[nj][ks] + 8192];
    if (IB1) stage_half(Bg + 128L * KK, (kt + 1) * 64, Bn + 8192, tid);
    __builtin_amdgcn_s_barrier();
    asm volatile("s_waitcnt lgkmcnt(0)" ::: "memory");
    __builtin_amdgcn_sched_barrier(0);
    __builtin_amdgcn_s_setprio(1);
#pragma unroll
    for (int mi = 0; mi < 4; ++mi)
#pragma unroll
        for (int nj = 0; nj < 2; ++nj)
#pragma unroll
            for (int ks = 0; ks < 2; ++ks)
                acc[0][mi][1][nj] = __builtin_amdgcn_mfma_f32_16x16x32_f16(
                    a[mi][ks], b[1][nj][ks], acc[0][mi][1][nj], 0, 0, 0);
    __builtin_amdgcn_s_setprio(0);
    __builtin_amdgcn_s_barrier();

    // ---- P3: quadrant (1,0) ----
#pragma unroll
    for (int mi = 0; mi < 4; ++mi)
#pragma unroll
        for (int ks = 0; ks < 2; ++ks)
            a[mi][ks] = *(const f16x8*)&Ac[aoff[mi][ks] + 8192];
    if (IA0) stage_half(Ag, (kt + 2) * 64, Ac, tid);
    __builtin_amdgcn_s_barrier();
    asm volatile("s_waitcnt lgkmcnt(0)" ::: "memory");
    __builtin_amdgcn_sched_barrier(0);
    __builtin_amdgcn_s_setprio(1);
#pragma unroll
    for (int mi = 0; mi < 4; ++mi)
#pragma unroll
        for (int nj = 0; nj < 2; ++nj)
#pragma unroll
            for (int ks = 0; ks < 2; ++ks)
                acc[1][mi][0][nj] = __builtin_amdgcn_mfma_f32_16x16x32_f16(
                    a[mi][ks], b[0][nj][ks], acc[1][mi][0][nj], 0, 0, 0);
    __builtin_amdgcn_s_setprio(0);
    __builtin_amdgcn_s_barrier();

    // ---- P4: quadrant (1,1) ----
    if (IB0) stage_half(Bg, (kt + 2) * 64, Bc, tid);
    __builtin_amdgcn_s_barrier();
    __builtin_amdgcn_s_setprio(1);
#pragma unroll
    for (int mi = 0; mi < 4; ++mi)
#pragma unroll
        for (int nj = 0; nj < 2; ++nj)
#pragma unroll
            for (int ks = 0; ks < 2; ++ks)
                acc[1][mi][1][nj] = __builtin_amdgcn_mfma_f32_16x16x32_f16(
                    a[mi][ks], b[1][nj][ks], acc[1][mi][1][nj], 0, 0, 0);
    __builtin_amdgcn_s_setprio(0);
    vwait<D1>();
    __builtin_amdgcn_s_barrier();
}

// C[m,n] = sum_k A[m,k]*Bm[n,k]; A:[M,KK] f16 rm, Bm:[N,KK] f16 rm, C f16 [M,N]
// grid 1D = Mtiles * (N/256), block 512 (8 waves: 2M x 4N), wave tile 128x64.
// Also writes Mg[row][bn] = max over this block's 256 cols of beta*C.
__global__ __launch_bounds__(512, 2) void gemm_bt_f16_256(
    const _Float16* __restrict__ A,
    const _Float16* __restrict__ Bm,
    _Float16* __restrict__ C,
    float* __restrict__ Mg,
    const float* __restrict__ beta_p,
    int Mtiles, int N)
{
    __shared__ _Float16 sm[65536];   // 128 KiB: [buf0 A][buf0 B][buf1 A][buf1 B]
    const int tid  = threadIdx.x;
    const int lane = tid & 63;
    const int wave = tid >> 6;
    const int wm = wave >> 2;        // 0..1
    const int wn = wave & 3;         // 0..3

    // XCD-aware swizzle; nwg = Mtiles*64 is a multiple of 8 -> bijective
    const int nwg = (int)gridDim.x;
    const int bid = (int)blockIdx.x;
    const int swz = (bid & 7) * (nwg >> 3) + (bid >> 3);
    const int bm = swz % Mtiles;
    const int bn = swz / Mtiles;

    const _Float16* Ag = A  + (long)bm * 256 * KK;
    const _Float16* Bg = Bm + (long)bn * 256 * KK;

    // fragment LDS offsets (halves): row R, chunk c=ks*4+(lane>>4),
    // slot=(c+(R&7))&7; mh=1 is a constant +8192 fold.
    const int r15 = lane & 15;
    const int kq  = lane >> 4;
    int aoff[4][2], boff[2][2];
#pragma unroll
    for (int mi = 0; mi < 4; ++mi)
#pragma unroll
        for (int ks = 0; ks < 2; ++ks) {
            int R = wm * 64 + mi * 16 + r15;
            int c = ks * 4 + kq;
            aoff[mi][ks] = R * 64 + (((c + (R & 7)) & 7) * 8);
        }
#pragma unroll
    for (int nj = 0; nj < 2; ++nj)
#pragma unroll
        for (int ks = 0; ks < 2; ++ks) {
            int R = wn * 32 + nj * 16 + r15;
            int c = ks * 4 + kq;
            boff[nj][ks] = R * 64 + (((c + (R & 7)) & 7) * 8);
        }

    _Float16* A0b = sm;
    _Float16* B0b = sm + 16384;
    _Float16* A1b = sm + 32768;
    _Float16* B1b = sm + 49152;

    f32x4 acc[2][4][2][2] = {};

    // prologue: A-lo(0),B-lo(0),A-hi(0),B-hi(0),A-lo(1),B-lo(1); drain to 8 ->
    // A-lo(0),B-lo(0) complete; in flight = steady state.
    stage_half(Ag,           0,  A0b,        tid);
    stage_half(Bg,           0,  B0b,        tid);
    stage_half(Ag + 128L*KK, 0,  A0b + 8192, tid);
    stage_half(Bg + 128L*KK, 0,  B0b + 8192, tid);
    stage_half(Ag,           64, A1b,        tid);
    stage_half(Bg,           64, B1b,        tid);
    vwait<8>();
    __builtin_amdgcn_s_barrier();

    for (int t = 0; t < NT - 2; t += 2) {
        tile_body<true,true,true,true,6,8>(A0b,B0b, A1b,B1b, Ag,Bg, t,   aoff,boff,tid,acc);
        tile_body<true,true,true,true,6,8>(A1b,B1b, A0b,B0b, Ag,Bg, t+1, aoff,boff,tid,acc);
    }
    // peeled tails (NT=16): tile 14 drains vmcnt(6)/vmcnt(4); tile 15 vmcnt(0).
    tile_body<true,true,false,false,6,4>(A0b,B0b, A1b,B1b, Ag,Bg, NT-2, aoff,boff,tid,acc);
    tile_body<false,false,false,false,0,-1>(A1b,B1b, A0b,B0b, Ag,Bg, NT-1, aoff,boff,tid,acc);

    // ---- segment-max sidecar: Mg[row][bn] = max over 256 cols of beta*C ----
    // C/D 16x16 layout: col = lane&15, row = (lane>>4)*4 + reg (validated by
    // passing C-store). LDS scratch 256x65 f32 (pad 65: final reduce would be
    // 32-way same-bank at stride 64). sm free after K-loop (ends in barrier).
    {
        float* sred = (float*)sm;
        const float beta = beta_p[0];
        const int g = lane >> 4;
#pragma unroll
        for (int mh = 0; mh < 2; ++mh)
#pragma unroll
        for (int mi = 0; mi < 4; ++mi)
#pragma unroll
        for (int reg = 0; reg < 4; ++reg) {
            float v =          beta * acc[mh][mi][0][0][reg];
            v = fmaxf(v, beta * acc[mh][mi][0][1][reg]);
            v = fmaxf(v, beta * acc[mh][mi][1][0][reg]);
            v = fmaxf(v, beta * acc[mh][mi][1][1][reg]);
            const int rl = mh * 128 + wm * 64 + mi * 16 + g * 4 + reg;
            sred[rl * 65 + wn * 16 + r15] = v;
        }
        __syncthreads();
        if (tid < 256) {
            float v = sred[tid * 65];
#pragma unroll
            for (int i = 1; i < 64; ++i) v = fmaxf(v, sred[tid * 65 + i]);
            Mg[((long)bm * 256 + tid) * 64 + bn] = v;
        }
    }

    // C-store (plain: scalar 2B stores rely on L2 write-combining — R4 lesson)
    const long rb0 = (long)bm * 256 + wm * 64 + (lane >> 4) * 4;
    const long cb0 = (long)bn * 256 + wn * 32 + (lane & 15);
#pragma unroll
    for (int mh = 0; mh < 2; ++mh)
#pragma unroll
    for (int mi = 0; mi < 4; ++mi)
#pragma unroll
    for (int nh = 0; nh < 2; ++nh)
#pragma unroll
    for (int nj = 0; nj < 2; ++nj) {
        const long r0 = rb0 + mh * 128 + mi * 16;
        const long c0 = cb0 + nh * 128 + nj * 16;
#pragma unroll
        for (int reg = 0; reg < 4; ++reg)
            C[(r0 + reg) * (long)N + c0] = (_Float16)acc[mh][mi][nh][nj][reg];
    }
}

// One WAVE per row (4 rows / 256-thr block). Reads 64 segment maxes, reduces
// -> m; scans only segments with Mseg >= m-15 for denominator + selection.
// Omitted mass <= N*3e-7 ~ 0.5% of l (same truncation bound as before).
__global__ __launch_bounds__(256) void softmax_gather2(
    const _Float16* __restrict__ S,   // [Rc, N] f16 logits (raw, pre-beta)
    const float* __restrict__ Mg,     // [Rc, 64] f32 per-segment max of beta*s
    const float* __restrict__ V,      // [N, D] fp32 text features
    const float* __restrict__ X,      // [Rc, D] (chunk-offset)
    float* __restrict__ Out,          // [Rc, D] (chunk-offset)
    const float* __restrict__ beta_p,
    const float* __restrict__ alpha_p,
    int N, int D)
{
    const int tid  = threadIdx.x;
    const int wave = tid >> 6;
    const int lane = tid & 63;
    const int row  = blockIdx.x * 4 + wave;
    const float beta  = beta_p[0];
    const float alpha = alpha_p[0];

    __shared__ int   s_idx[4][SELCAP];
    __shared__ float s_w[4][SELCAP];
    __shared__ int   s_cnt[4];
    if (lane == 0) s_cnt[wave] = 0;   // wave-local; DS ops in-order per wave

    float Mv = Mg[(size_t)row * 64 + lane];   // 64 segments == 64 lanes
    float m = Mv;
#pragma unroll
    for (int off = 32; off; off >>= 1) m = fmaxf(m, __shfl_xor(m, off));

    unsigned long long qual = __ballot(Mv >= m - 15.f);   // uniform across wave
    float l = 0.f;
    const _Float16* srow = S + (size_t)row * N;
    while (qual) {
        const int s = __ffsll(qual) - 1;
        qual &= qual - 1;
        const f16x4 h = *(const f16x4*)(srow + s * 256 + lane * 4);
#pragma unroll
        for (int c = 0; c < 4; ++c) {
            const float e = fexp2((beta * (float)h[c] - m) * LOG2E);
            l += e;
            if (e >= 3.0e-7f) {
                int p = atomicAdd(&s_cnt[wave], 1);
                if (p < SELCAP) {
                    s_idx[wave][p] = s * 256 + lane * 4 + c;
                    s_w[wave][p]   = e;
                }
            }
        }
    }
#pragma unroll
    for (int off = 32; off; off >>= 1) l += __shfl_xor(l, off);

    int nsel = s_cnt[wave]; if (nsel > SELCAP) nsel = SELCAP;
    const float wsc = alpha / l;

    f32x4 a0 = {0,0,0,0}, a1 = {0,0,0,0}, a2 = {0,0,0,0}, a3 = {0,0,0,0};
    for (int i = 0; i < nsel; ++i) {
        const float w = s_w[wave][i] * wsc;
        const float* vp = V + (size_t)s_idx[wave][i] * D + lane * 4;
        a0 += w * *(const f32x4*)(vp);
        a1 += w * *(const f32x4*)(vp + 256);
        a2 += w * *(const f32x4*)(vp + 512);
        a3 += w * *(const f32x4*)(vp + 768);
    }
    const float* xp = X + (size_t)row * D + lane * 4;
    float* op = Out + (size_t)row * D + lane * 4;
    f32x4 o0 = *(const f32x4*)(xp)       + a0;
    f32x4 o1 = *(const f32x4*)(xp + 256) + a1;
    f32x4 o2 = *(const f32x4*)(xp + 512) + a2;
    f32x4 o3 = *(const f32x4*)(xp + 768) + a3;
    __builtin_nontemporal_store(o0, (f32x4*)(op));
    __builtin_nontemporal_store(o1, (f32x4*)(op + 256));
    __builtin_nontemporal_store(o2, (f32x4*)(op + 512));
    __builtin_nontemporal_store(o3, (f32x4*)(op + 768));
}

extern "C" void kernel_launch(void* const* d_in, const int* in_sizes, int n_in,
                              void* d_out, int out_size, void* d_ws, size_t ws_size,
                              hipStream_t stream) {
    const float* x     = (const float*)d_in[0];
    const float* kimg  = (const float*)d_in[1];
    const float* vtxt  = (const float*)d_in[2];
    const float* beta  = (const float*)d_in[3];
    const float* alpha = (const float*)d_in[4];
    float* out = (float*)d_out;

    const int D = 1024;
    const int B = in_sizes[0] / D;   // 4096
    const int N = in_sizes[1] / D;   // 16384

    char* ws = (char*)d_ws;
    _Float16* x16 = (_Float16*)ws;
    _Float16* k16 = (_Float16*)(ws + (size_t)B * D * 2);
    float*    Mg  = (float*)   (ws + (size_t)B * D * 2 + (size_t)N * D * 2);
    _Float16* S   = (_Float16*)(ws + (size_t)B * D * 2 + (size_t)N * D * 2
                                   + (size_t)B * 64 * 4);

    const size_t fixed = (size_t)B * D * 2 + (size_t)N * D * 2 + (size_t)B * 64 * 4;
    size_t avail = ws_size > fixed ? ws_size - fixed : 0;
    long Rl = (long)(avail / ((size_t)N * 2));
    Rl &= ~255L;
    int R = (int)(Rl > B ? B : Rl);
    if (R < 256) R = 256;

    {
        long nx4 = (long)B * D / 4;
        long nk4 = (long)N * D / 4;
        long tot = nk4 + nx4;
        convert2<<<(unsigned)((tot + 255) / 256), 256, 0, stream>>>(kimg, k16, nk4, x, x16, nx4);
    }

    for (int r0 = 0; r0 < B; r0 += R) {
        int Rc = B - r0; if (Rc > R) Rc = R;
        int Mtiles = Rc / 256;
        dim3 g1((unsigned)(Mtiles * (N / 256)));
        gemm_bt_f16_256<<<g1, 512, 0, stream>>>(x16 + (size_t)r0 * D, k16, S, Mg, beta, Mtiles, N);
        softmax_gather2<<<(unsigned)(Rc / 4), 256, 0, stream>>>(
            S, Mg, vtxt, x + (size_t)r0 * D, out + (size_t)r0 * D, beta, alpha, N, D);
    }
}

// Round 6
// 317.718 us; speedup vs baseline: 1.0401x; 1.0401x over previous
//
#include <hip/hip_runtime.h>

// out = x + alpha * softmax(beta * x @ K^T) @ V
// B=4096, N=16384, D=1024, fp32 in/out.
// R8 changes vs R7:
//  - Drop Mg sidecar + sparse softmax (R7 proved residual is NOT softmax data
//    volume: 128MB->5MB S-reads moved total +1.4us; sidecar cost GEMM +5.3us).
//    Softmax reverts to R6's 512-thr full-scan (equally neutral, zero GEMM cost).
//  - GEMM -> PERSISTENT blocks: grid = 16*Mtiles (1/CU), each block owns 4
//    output tiles (fixed bm, consecutive bn). The 8-phase schedule runs
//    continuously across 64 K-steps; kt+1/kt+2 prefetch stages cross tile
//    boundaries naturally (only B pointer advances; A panel L2-reused 4x).
//    C-stores issued at tile boundaries with NO wait -> overlap next tile's
//    compute (stores inflate vmcnt -> counted vwaits strictly more
//    conservative -> safe). Removes 3 of 4 pipeline fills + un-exposes the
//    epilogue (was fully exposed at 1 block/CU).
//  - XCD mapping: xcd=bid%8 covers a compact bn range; 16 blocks/XCD share
//    the same 4 B panels in L2.

typedef float    f32x4  __attribute__((ext_vector_type(4)));
typedef _Float16 f16x8  __attribute__((ext_vector_type(8)));
typedef _Float16 f16x4  __attribute__((ext_vector_type(4)));

#define LOG2E 1.44269504088896340736f
#define KK 1024   // K (= D) fixed for this problem shape
#define TT 4      // output tiles per persistent block
#define NTT (TT*16)

__device__ __forceinline__ void lds_load16(const void* g, void* l) {
    __builtin_amdgcn_global_load_lds(
        (__attribute__((address_space(1))) void*)(uintptr_t)g,
        (__attribute__((address_space(3))) void*)l,
        16, 0, 0);
}

template<int N> __device__ __forceinline__ void vwait() {
    if constexpr (N == 8)      asm volatile("s_waitcnt vmcnt(8)" ::: "memory");
    else if constexpr (N == 6) asm volatile("s_waitcnt vmcnt(6)" ::: "memory");
    else if constexpr (N == 4) asm volatile("s_waitcnt vmcnt(4)" ::: "memory");
    else if constexpr (N == 0) asm volatile("s_waitcnt vmcnt(0)" ::: "memory");
    // N == -1: no wait
}

__device__ __forceinline__ float fexp2(float x) {
    float r; asm("v_exp_f32 %0, %1" : "=v"(r) : "v"(x)); return r;
}

__global__ void convert2(const float* __restrict__ a, _Float16* __restrict__ oa, long na4,
                         const float* __restrict__ b, _Float16* __restrict__ ob, long nb4) {
    long i = (long)blockIdx.x * blockDim.x + threadIdx.x;
    if (i < na4) {
        ((f16x4*)oa)[i] = __builtin_convertvector(((const f32x4*)a)[i], f16x4);
    } else {
        long j = i - na4;
        if (j < nb4) ((f16x4*)ob)[j] = __builtin_convertvector(((const f32x4*)b)[j], f16x4);
    }
}

// Stage one half-tile (128 rows x 64 halves) of row-major [*, KK] f16 into LDS.
// LDS side lane-linear (global_load_lds requirement); chunk rotation
// slot=(chunk+row)&7 realized by rotating the GLOBAL source column.
// One call = 2 vmcnt entries.
__device__ __forceinline__ void stage_half(const _Float16* __restrict__ g,
                                           int k0, _Float16* lds_half, int tid) {
    const int r = tid >> 3;                        // 0..63
    const int c = ((tid & 7) - (r & 7)) & 7;       // source chunk for slot tid&7
    const _Float16* s0 = g + (long)r * KK + k0 + c * 8;
    _Float16* d = lds_half + (tid >> 6) * 512;     // wave-uniform base; HW adds lane*16B
    lds_load16(s0, d);
    lds_load16(s0 + 64 * KK, d + 4096);
}

// One K-step (BK=64) of the 8-phase schedule (reads at phase head, barrier +
// lgkmcnt(0) hides their latency — R5 isolation). Ac/Bc: current LDS buffer;
// An/Bn: other. Stage targets generalized for the persistent loop:
//   P1 stages A-hi(step g+1) @ k1; P2 stages B-hi(g+1) from Bg1 @ k1;
//   P3 stages A-lo(step g+2) @ k2; P4 stages B-lo(g+2) from Bg2 @ k2.
template<bool IA1, bool IB1, bool IA0, bool IB0, int D2, int D1>
__device__ __forceinline__ void tile_body(
    _Float16* Ac, _Float16* Bc, _Float16* An, _Float16* Bn,
    const _Float16* __restrict__ Ag,
    const _Float16* __restrict__ Bg1,
    const _Float16* __restrict__ Bg2,
    int k1, int k2,
    const int (&aoff)[4][2], const int (&boff)[2][2],
    int tid, f32x4 (&acc)[2][4][2][2])
{
    f16x8 a[4][2];
    f16x8 b[2][2][2];

    // ---- P1: quadrant (mh=0, nh=0) ----
#pragma unroll
    for (int mi = 0; mi < 4; ++mi)
#pragma unroll
        for (int ks = 0; ks < 2; ++ks)
            a[mi][ks] = *(const f16x8*)&Ac[aoff[mi][ks]];
#pragma unroll
    for (int nj = 0; nj < 2; ++nj)
#pragma unroll
        for (int ks = 0; ks < 2; ++ks)
            b[0][nj][ks] = *(const f16x8*)&Bc[boff[nj][ks]];
    if (IA1) stage_half(Ag + 128L * KK, k1, An + 8192, tid);
    __builtin_amdgcn_s_barrier();
    asm volatile("s_waitcnt lgkmcnt(0)" ::: "memory");
    __builtin_amdgcn_sched_barrier(0);
    __builtin_amdgcn_s_setprio(1);
#pragma unroll
    for (int mi = 0; mi < 4; ++mi)
#pragma unroll
        for (int nj = 0; nj < 2; ++nj)
#pragma unroll
            for (int ks = 0; ks < 2; ++ks)
                acc[0][mi][0][nj] = __builtin_amdgcn_mfma_f32_16x16x32_f16(
                    a[mi][ks], b[0][nj][ks], acc[0][mi][0][nj], 0, 0, 0);
    __builtin_amdgcn_s_setprio(0);
    vwait<D2>();
    __builtin_amdgcn_s_barrier();

    // ---- P2: quadrant (0,1) ----
#pragma unroll
    for (int nj = 0; nj < 2; ++nj)
#pragma unroll
        for (int ks = 0; ks < 2; ++ks)
            b[1][nj][ks] = *(const f16x8*)&Bc[boff[nj][ks] + 8192];
    if (IB1) stage_half(Bg1 + 128L * KK, k1, Bn + 8192, tid);
    __builtin_amdgcn_s_barrier();
    asm volatile("s_waitcnt lgkmcnt(0)" ::: "memory");
    __builtin_amdgcn_sched_barrier(0);
    __builtin_amdgcn_s_setprio(1);
#pragma unroll
    for (int mi = 0; mi < 4; ++mi)
#pragma unroll
        for (int nj = 0; nj < 2; ++nj)
#pragma unroll
            for (int ks = 0; ks < 2; ++ks)
                acc[0][mi][1][nj] = __builtin_amdgcn_mfma_f32_16x16x32_f16(
                    a[mi][ks], b[1][nj][ks], acc[0][mi][1][nj], 0, 0, 0);
    __builtin_amdgcn_s_setprio(0);
    __builtin_amdgcn_s_barrier();

    // ---- P3: quadrant (1,0) ----
#pragma unroll
    for (int mi = 0; mi < 4; ++mi)
#pragma unroll
        for (int ks = 0; ks < 2; ++ks)
            a[mi][ks] = *(const f16x8*)&Ac[aoff[mi][ks] + 8192];
    if (IA0) stage_half(Ag, k2, Ac, tid);
    __builtin_amdgcn_s_barrier();
    asm volatile("s_waitcnt lgkmcnt(0)" ::: "memory");
    __builtin_amdgcn_sched_barrier(0);
    __builtin_amdgcn_s_setprio(1);
#pragma unroll
    for (int mi = 0; mi < 4; ++mi)
#pragma unroll
        for (int nj = 0; nj < 2; ++nj)
#pragma unroll
            for (int ks = 0; ks < 2; ++ks)
                acc[1][mi][0][nj] = __builtin_amdgcn_mfma_f32_16x16x32_f16(
                    a[mi][ks], b[0][nj][ks], acc[1][mi][0][nj], 0, 0, 0);
    __builtin_amdgcn_s_setprio(0);
    __builtin_amdgcn_s_barrier();

    // ---- P4: quadrant (1,1) ----
    if (IB0) stage_half(Bg2, k2, Bc, tid);
    __builtin_amdgcn_s_barrier();
    __builtin_amdgcn_s_setprio(1);
#pragma unroll
    for (int mi = 0; mi < 4; ++mi)
#pragma unroll
        for (int nj = 0; nj < 2; ++nj)
#pragma unroll
            for (int ks = 0; ks < 2; ++ks)
                acc[1][mi][1][nj] = __builtin_amdgcn_mfma_f32_16x16x32_f16(
                    a[mi][ks], b[1][nj][ks], acc[1][mi][1][nj], 0, 0, 0);
    __builtin_amdgcn_s_setprio(0);
    vwait<D1>();
    __builtin_amdgcn_s_barrier();
}

// Store one 256x256 tile from acc, then zero acc. Stores are fire-and-forget
// (no wait); they overlap the next tile's compute. Plain stores (L2
// write-combining — R4 lesson).
__device__ __forceinline__ void store_tile(
    _Float16* __restrict__ C, f32x4 (&acc)[2][4][2][2],
    long rb0, long cb0, int N)
{
#pragma unroll
    for (int mh = 0; mh < 2; ++mh)
#pragma unroll
    for (int mi = 0; mi < 4; ++mi)
#pragma unroll
    for (int nh = 0; nh < 2; ++nh)
#pragma unroll
    for (int nj = 0; nj < 2; ++nj) {
        const long r0 = rb0 + mh * 128 + mi * 16;
        const long c0 = cb0 + nh * 128 + nj * 16;
#pragma unroll
        for (int reg = 0; reg < 4; ++reg)
            C[(r0 + reg) * (long)N + c0] = (_Float16)acc[mh][mi][nh][nj][reg];
    }
#pragma unroll
    for (int mh = 0; mh < 2; ++mh)
#pragma unroll
    for (int mi = 0; mi < 4; ++mi)
#pragma unroll
    for (int nh = 0; nh < 2; ++nh)
#pragma unroll
    for (int nj = 0; nj < 2; ++nj)
        acc[mh][mi][nh][nj] = (f32x4){0.f, 0.f, 0.f, 0.f};
}

// C[m,n] = sum_k A[m,k]*Bm[n,k]; A:[M,KK] f16 rm, Bm:[N,KK] f16 rm, C f16 [M,N]
// PERSISTENT: grid = Mtiles*16 blocks (1/CU at Mtiles=16), block 512 (8 waves:
// 2M x 4N). Each block: 4 tiles at fixed bm, bn = bn0..bn0+3, run as one
// continuous 64-K-step pipeline.
__global__ __launch_bounds__(512, 2) void gemm_bt_f16_256(
    const _Float16* __restrict__ A,
    const _Float16* __restrict__ Bm,
    _Float16* __restrict__ C,
    int Mtiles, int N)
{
    __shared__ _Float16 sm[65536];   // 128 KiB: [buf0 A][buf0 B][buf1 A][buf1 B]
    const int tid  = threadIdx.x;
    const int lane = tid & 63;
    const int wave = tid >> 6;
    const int wm = wave >> 2;        // 0..1
    const int wn = wave & 3;         // 0..3

    // XCD-compact tile assignment: xcd = bid%8 (HW round-robin heuristic).
    // Per XCD: 2*Mtiles blocks covering bn in [xcd*8, xcd*8+8) x all bm.
    const int bid = (int)blockIdx.x;
    const int xcd = bid & 7;
    const int j   = bid >> 3;                // 0 .. 2*Mtiles-1
    const int bm  = j % Mtiles;
    const int c4  = j / Mtiles;              // 0..1
    const int bn0 = xcd * 8 + c4 * 4;        // 4 consecutive bn

    const _Float16* Ag  = A  + (long)bm * 256 * KK;
    const long BSTR = 256L * KK;
    const _Float16* Bg0 = Bm + (long)bn0 * BSTR;   // tile i: Bg0 + i*BSTR

    // fragment LDS offsets (halves): row R, chunk ck=ks*4+(lane>>4),
    // slot=(ck+(R&7))&7; mh=1 is a constant +8192 fold.
    const int r15 = lane & 15;
    const int kq  = lane >> 4;
    int aoff[4][2], boff[2][2];
#pragma unroll
    for (int mi = 0; mi < 4; ++mi)
#pragma unroll
        for (int ks = 0; ks < 2; ++ks) {
            int R = wm * 64 + mi * 16 + r15;
            int ck = ks * 4 + kq;
            aoff[mi][ks] = R * 64 + (((ck + (R & 7)) & 7) * 8);
        }
#pragma unroll
    for (int nj = 0; nj < 2; ++nj)
#pragma unroll
        for (int ks = 0; ks < 2; ++ks) {
            int R = wn * 32 + nj * 16 + r15;
            int ck = ks * 4 + kq;
            boff[nj][ks] = R * 64 + (((ck + (R & 7)) & 7) * 8);
        }

    _Float16* A0b = sm;
    _Float16* B0b = sm + 16384;
    _Float16* A1b = sm + 32768;
    _Float16* B1b = sm + 49152;

    f32x4 acc[2][4][2][2] = {};

    const long rb0 = (long)bm * 256 + wm * 64 + (lane >> 4) * 4;
    const long cbb = (long)bn0 * 256 + wn * 32 + r15;

    // prologue (tile 0): A-lo(0),B-lo(0),A-hi(0),B-hi(0),A-lo(1),B-lo(1);
    // drain to 8 -> A-lo(0),B-lo(0) complete; in flight = steady state.
    stage_half(Ag,           0,  A0b,        tid);
    stage_half(Bg0,          0,  B0b,        tid);
    stage_half(Ag + 128L*KK, 0,  A0b + 8192, tid);
    stage_half(Bg0 + 128L*KK,0,  B0b + 8192, tid);
    stage_half(Ag,           64, A1b,        tid);
    stage_half(Bg0,          64, B1b,        tid);
    vwait<8>();
    __builtin_amdgcn_s_barrier();

    // continuous pipeline over NTT = 64 K-steps (4 tiles x 16)
    for (int g = 0; g < NTT - 2; g += 2) {
        {
            const int k1 = ((g + 1) & 15) * 64, k2 = ((g + 2) & 15) * 64;
            const _Float16* B1p = Bg0 + (long)((g + 1) >> 4) * BSTR;
            const _Float16* B2p = Bg0 + (long)((g + 2) >> 4) * BSTR;
            tile_body<true,true,true,true,6,8>(A0b,B0b, A1b,B1b, Ag, B1p, B2p,
                                               k1, k2, aoff,boff,tid,acc);
        }
        {
            const int k1 = ((g + 2) & 15) * 64, k2 = ((g + 3) & 15) * 64;
            const _Float16* B1p = Bg0 + (long)((g + 2) >> 4) * BSTR;
            const _Float16* B2p = Bg0 + (long)((g + 3) >> 4) * BSTR;
            tile_body<true,true,true,true,6,8>(A1b,B1b, A0b,B0b, Ag, B1p, B2p,
                                               k1, k2, aoff,boff,tid,acc);
        }
        // tile boundary: step g+1 ended a tile (g+1 = 15, 31, 47) -> store it,
        // fire-and-forget (stores only make subsequent counted vwaits stricter)
        if (((g + 1) & 15) == 15)
            store_tile(C, acc, rb0, cbb + (long)((g + 1) >> 4) * 256, N);
    }
    // peeled tail: step NTT-2 stages hi(NTT-1) then drains 6/4; NTT-1 drains 0.
    {
        const int k1 = ((NTT - 1) & 15) * 64;
        const _Float16* B1p = Bg0 + (long)((NTT - 1) >> 4) * BSTR;
        tile_body<true,true,false,false,6,4>(A0b,B0b, A1b,B1b, Ag, B1p, B1p,
                                             k1, 0, aoff,boff,tid,acc);
    }
    tile_body<false,false,false,false,0,-1>(A1b,B1b, A0b,B0b, Ag, Bg0, Bg0,
                                            0, 0, aoff,boff,tid,acc);
    store_tile(C, acc, rb0, cbb + (long)(TT - 1) * 256, N);
}

// One workgroup (512 thr, 8 waves) per row; S is f16 [Rc, N], N=16384.
// (R6 version — proven neutral; sparse variant bought nothing, R7.)
__global__ __launch_bounds__(512) void softmax_gather(
    const _Float16* __restrict__ S,
    const float* __restrict__ V,     // [N, D] fp32 text features
    const float* __restrict__ X,     // [Rc, D] (chunk-offset)
    float* __restrict__ Out,         // [Rc, D] (chunk-offset)
    const float* __restrict__ beta_p,
    const float* __restrict__ alpha_p,
    int N, int D)
{
    const int row  = blockIdx.x;
    const int tid  = threadIdx.x;
    const int lane = tid & 63;
    const int wave = tid >> 6;       // 0..7
    const float beta  = beta_p[0];
    const float alpha = alpha_p[0];

    __shared__ float redm[8];
    __shared__ float redl[8];
    __shared__ int   cnt;
    __shared__ int   sel_idx[1024];
    __shared__ float sel_w[1024];

    const f16x8* s8 = (const f16x8*)(S + (size_t)row * N);

    // 4 chunks of 8 halves per thread = 32 logits, held as f32x4 v[8]
    f32x4 v[8];
    float m = -3.4e38f;
#pragma unroll
    for (int j = 0; j < 4; ++j) {
        f16x8 h = s8[tid + j * 512];
        f32x4 lo, hiv;
#pragma unroll
        for (int c = 0; c < 4; ++c) { lo[c] = (float)h[c] * beta; hiv[c] = (float)h[c + 4] * beta; }
        v[2 * j] = lo; v[2 * j + 1] = hiv;
        m = fmaxf(m, fmaxf(fmaxf(lo[0], lo[1]), fmaxf(lo[2], lo[3])));
        m = fmaxf(m, fmaxf(fmaxf(hiv[0], hiv[1]), fmaxf(hiv[2], hiv[3])));
    }
    const float lm = m;   // thread-local max (pre-reduction)
#pragma unroll
    for (int off = 32; off; off >>= 1) m = fmaxf(m, __shfl_xor(m, off));
    if (lane == 0) redm[wave] = m;
    if (tid == 0) cnt = 0;
    __syncthreads();
    m = fmaxf(fmaxf(fmaxf(redm[0], redm[1]), fmaxf(redm[2], redm[3])),
              fmaxf(fmaxf(redm[4], redm[5]), fmaxf(redm[6], redm[7])));

    // threads whose 32 logits are all < m-15 contribute <= 32*3e-7 to l and
    // nothing to the selection; skip their exp pass (l err <= 0.5%).
    const bool active = (lm >= m - 15.f);
    float l = 0.f;
    if (active) {
#pragma unroll
        for (int j = 0; j < 8; ++j) {
            f32x4 e;
#pragma unroll
            for (int c = 0; c < 4; ++c) e[c] = fexp2((v[j][c] - m) * LOG2E);
            l += e[0] + e[1] + e[2] + e[3];
            v[j] = e;
        }
    }
#pragma unroll
    for (int off = 32; off; off >>= 1) l += __shfl_xor(l, off);
    if (lane == 0) redl[wave] = l;
    __syncthreads();
    l = redl[0] + redl[1] + redl[2] + redl[3] + redl[4] + redl[5] + redl[6] + redl[7];

    if (active) {
#pragma unroll
        for (int j = 0; j < 8; ++j) {
#pragma unroll
            for (int c = 0; c < 4; ++c) {
                float e = v[j][c];
                if (e >= 3.0e-7f) {
                    int p = atomicAdd(&cnt, 1);
                    if (p < 1024) {
                        sel_idx[p] = (tid + (j >> 1) * 512) * 8 + (j & 1) * 4 + c;
                        sel_w[p]   = e;
                    }
                }
            }
        }
    }
    __syncthreads();
    int nsel = cnt; if (nsel > 1024) nsel = 1024;

    const float wscale = alpha / l;
    typedef float f32x2 __attribute__((ext_vector_type(2)));
    f32x2 acc = {0.f, 0.f};
    for (int i = 0; i < nsel; ++i) {
        const float w = sel_w[i] * wscale;
        const f32x2 t = *(const f32x2*)(V + (size_t)sel_idx[i] * D + tid * 2);
        acc += w * t;
    }
    const f32x2 xr = ((const f32x2*)(X + (size_t)row * D))[tid];
    f32x2 o = xr + acc;
    __builtin_nontemporal_store(o, (f32x2*)(Out + (size_t)row * D) + tid);
}

extern "C" void kernel_launch(void* const* d_in, const int* in_sizes, int n_in,
                              void* d_out, int out_size, void* d_ws, size_t ws_size,
                              hipStream_t stream) {
    const float* x     = (const float*)d_in[0];
    const float* kimg  = (const float*)d_in[1];
    const float* vtxt  = (const float*)d_in[2];
    const float* beta  = (const float*)d_in[3];
    const float* alpha = (const float*)d_in[4];
    float* out = (float*)d_out;

    const int D = 1024;
    const int B = in_sizes[0] / D;   // 4096
    const int N = in_sizes[1] / D;   // 16384

    char* ws = (char*)d_ws;
    _Float16* x16 = (_Float16*)ws;
    _Float16* k16 = (_Float16*)(ws + (size_t)B * D * 2);
    _Float16* S   = (_Float16*)(ws + (size_t)B * D * 2 + (size_t)N * D * 2);

    const size_t fixed = (size_t)B * D * 2 + (size_t)N * D * 2;
    size_t avail = ws_size > fixed ? ws_size - fixed : 0;
    long Rl = (long)(avail / ((size_t)N * 2));
    Rl &= ~255L;
    int R = (int)(Rl > B ? B : Rl);
    if (R < 256) R = 256;

    {
        long nx4 = (long)B * D / 4;
        long nk4 = (long)N * D / 4;
        long tot = nk4 + nx4;
        convert2<<<(unsigned)((tot + 255) / 256), 256, 0, stream>>>(kimg, k16, nk4, x, x16, nx4);
    }

    for (int r0 = 0; r0 < B; r0 += R) {
        int Rc = B - r0; if (Rc > R) Rc = R;
        int Mtiles = Rc / 256;
        dim3 g1((unsigned)(Mtiles * 16));   // persistent: 4 tiles/block
        gemm_bt_f16_256<<<g1, 512, 0, stream>>>(x16 + (size_t)r0 * D, k16, S, Mtiles, N);
        softmax_gather<<<(unsigned)Rc, 512, 0, stream>>>(
            S, vtxt, x + (size_t)r0 * D, out + (size_t)r0 * D, beta, alpha, N, D);
    }
}